// Round 4
// baseline (558.027 us; speedup 1.0000x reference)
//
#include <hip/hip_runtime.h>

#define N_NODES 32768
#define EMBED   512
#define NNZ_TOT 1048576
#define LN_EPS  1e-5f

typedef __attribute__((ext_vector_type(8))) short bf16x8;
typedef __attribute__((ext_vector_type(4))) float f32x4;
typedef __attribute__((ext_vector_type(4))) unsigned int u32x4;

__device__ __forceinline__ unsigned short f2bf(float x) {
    unsigned int u = __float_as_uint(x);
    unsigned int r = u + 0x7fffu + ((u >> 16) & 1u);   // RNE
    return (unsigned short)(r >> 16);
}
__device__ __forceinline__ unsigned int pk2(float a, float b) {
    return (unsigned int)f2bf(a) | ((unsigned int)f2bf(b) << 16);
}

// ---------------- zero scratch ints ----------------
__global__ void zero_ints(int* __restrict__ p, int n) {
    int i = blockIdx.x * blockDim.x + threadIdx.x;
    if (i < n) p[i] = 0;
}

// ---------------- W [k][n] fp32 -> Wt [n][k] bf16 ----------------
__global__ __launch_bounds__(256) void wt_kernel(
    const float* __restrict__ W, unsigned short* __restrict__ Wt)
{
    __shared__ float tile[32][33];
    const int tx = threadIdx.x & 31, ty = threadIdx.x >> 5;  // ty 0..7
    const int kb = blockIdx.y * 32, nb = blockIdx.x * 32;
#pragma unroll
    for (int i = 0; i < 32; i += 8)
        tile[ty + i][tx] = W[(long)(kb + ty + i) * EMBED + nb + tx];
    __syncthreads();
#pragma unroll
    for (int i = 0; i < 32; i += 8)
        Wt[(long)(nb + ty + i) * EMBED + kb + tx] = f2bf(tile[tx][ty + i]);
}

// ---------------- gather + bf16 MFMA GEMM, software-pipelined double buffer ----------------
// 128x128 tile, BK=32, 256 threads = 4 waves 2x2, each wave 64x64 via 4x4 mfma 16x16x32.
// Global loads for iter k+1 issue before the MFMA phase of iter k -> HBM latency hidden.
__global__ __launch_bounds__(256) void gemm_mfma(
    const int* __restrict__ uids, const float* __restrict__ emb,
    const unsigned short* __restrict__ Wt, unsigned short* __restrict__ support)
{
    __shared__ unsigned short As[2][128][40];   // stride 40: 2-way bank alias only (free)
    __shared__ unsigned short Bs[2][128][40];

    const int t  = threadIdx.x;
    const int m0 = blockIdx.y * 128;
    const int n0 = blockIdx.x * 128;

    const int wave = t >> 6;
    const int lane = t & 63;
    const int wm   = (wave & 1) * 64;
    const int wn   = (wave >> 1) * 64;
    const int l16  = lane & 15;
    const int quad = lane >> 4;

    const int srow  = t >> 1;
    const int shalf = (t & 1) * 16;
    const int uid   = uids[m0 + srow];
    const float* arow = emb + (long)uid * EMBED + shalf;
    const unsigned short* brow = Wt + (long)(n0 + srow) * EMBED + shalf;

    f32x4 acc[4][4] = {};

    // prologue: load + stage iter 0 into buffer 0
    {
        const float4* ap = (const float4*)arow;
        float4 v0 = ap[0], v1 = ap[1], v2 = ap[2], v3 = ap[3];
        const u32x4* bp = (const u32x4*)brow;
        u32x4 b0 = bp[0], b1 = bp[1];
        u32x4 lo, hi;
        lo.x = pk2(v0.x, v0.y); lo.y = pk2(v0.z, v0.w);
        lo.z = pk2(v1.x, v1.y); lo.w = pk2(v1.z, v1.w);
        hi.x = pk2(v2.x, v2.y); hi.y = pk2(v2.z, v2.w);
        hi.z = pk2(v3.x, v3.y); hi.w = pk2(v3.z, v3.w);
        *(u32x4*)&As[0][srow][shalf]     = lo;
        *(u32x4*)&As[0][srow][shalf + 8] = hi;
        *(u32x4*)&Bs[0][srow][shalf]     = b0;
        *(u32x4*)&Bs[0][srow][shalf + 8] = b1;
    }
    __syncthreads();

    for (int k = 0; k < 16; ++k) {
        const int cur = k & 1;

        // issue next iteration's global loads FIRST (in flight across the MFMAs)
        float4 nv0, nv1, nv2, nv3;
        u32x4 nb0, nb1;
        if (k < 15) {
            const float4* ap = (const float4*)(arow + (k + 1) * 32);
            nv0 = ap[0]; nv1 = ap[1]; nv2 = ap[2]; nv3 = ap[3];
            const u32x4* bp = (const u32x4*)(brow + (k + 1) * 32);
            nb0 = bp[0]; nb1 = bp[1];
        }

        bf16x8 af[4], bfr[4];
#pragma unroll
        for (int i = 0; i < 4; ++i)
            af[i] = *(const bf16x8*)&As[cur][wm + i * 16 + l16][quad * 8];
#pragma unroll
        for (int j = 0; j < 4; ++j)
            bfr[j] = *(const bf16x8*)&Bs[cur][wn + j * 16 + l16][quad * 8];
#pragma unroll
        for (int i = 0; i < 4; ++i)
#pragma unroll
            for (int j = 0; j < 4; ++j)
                acc[i][j] = __builtin_amdgcn_mfma_f32_16x16x32_bf16(af[i], bfr[j], acc[i][j], 0, 0, 0);

        if (k < 15) {
            u32x4 lo, hi;
            lo.x = pk2(nv0.x, nv0.y); lo.y = pk2(nv0.z, nv0.w);
            lo.z = pk2(nv1.x, nv1.y); lo.w = pk2(nv1.z, nv1.w);
            hi.x = pk2(nv2.x, nv2.y); hi.y = pk2(nv2.z, nv2.w);
            hi.z = pk2(nv3.x, nv3.y); hi.w = pk2(nv3.z, nv3.w);
            const int nxt = cur ^ 1;
            *(u32x4*)&As[nxt][srow][shalf]     = lo;
            *(u32x4*)&As[nxt][srow][shalf + 8] = hi;
            *(u32x4*)&Bs[nxt][srow][shalf]     = nb0;
            *(u32x4*)&Bs[nxt][srow][shalf + 8] = nb1;
            __syncthreads();
        }
    }

    // epilogue: C/D layout col=lane&15, row=quad*4+reg
#pragma unroll
    for (int i = 0; i < 4; ++i) {
#pragma unroll
        for (int j = 0; j < 4; ++j) {
            const int col = n0 + wn + j * 16 + l16;
#pragma unroll
            for (int r = 0; r < 4; ++r) {
                const int row = m0 + wm + i * 16 + quad * 4 + r;
                support[(long)row * EMBED + col] = f2bf(acc[i][j][r]);
            }
        }
    }
}

// ---------------- CSR build ----------------
__global__ void hist_kernel(const int4* __restrict__ adj_row4, int* __restrict__ counts) {
    int i = blockIdx.x * blockDim.x + threadIdx.x;   // i < NNZ/4
    int4 r = adj_row4[i];
    atomicAdd(&counts[r.x], 1);
    atomicAdd(&counts[r.y], 1);
    atomicAdd(&counts[r.z], 1);
    atomicAdd(&counts[r.w], 1);
}

__global__ __launch_bounds__(1024) void scan_kernel(
    const int* __restrict__ counts, int* __restrict__ row_start)
{
    __shared__ int ssum[1024];
    const int t = threadIdx.x;
    const int base = t * 32;
    int loc[32];
    int run = 0;
    const int4* c4 = (const int4*)(counts + base);
#pragma unroll
    for (int i = 0; i < 8; ++i) {
        int4 c = c4[i];
        loc[4 * i]     = run; run += c.x;
        loc[4 * i + 1] = run; run += c.y;
        loc[4 * i + 2] = run; run += c.z;
        loc[4 * i + 3] = run; run += c.w;
    }
    ssum[t] = run;
    __syncthreads();
    for (int off = 1; off < 1024; off <<= 1) {
        int v = (t >= off) ? ssum[t - off] : 0;
        __syncthreads();
        ssum[t] += v;
        __syncthreads();
    }
    int prefix = (t > 0) ? ssum[t - 1] : 0;
#pragma unroll
    for (int i = 0; i < 32; ++i) row_start[base + i] = prefix + loc[i];
    if (t == 1023) row_start[N_NODES] = ssum[1023];
}

__global__ void scatter_kernel(
    const int4* __restrict__ adj_row4, const int4* __restrict__ adj_col4,
    const float4* __restrict__ adj_vals4, const int* __restrict__ row_start,
    int* __restrict__ cursor, int2* __restrict__ sc)
{
    int i = blockIdx.x * blockDim.x + threadIdx.x;   // i < NNZ/4
    int4  r = adj_row4[i];
    int4  c = adj_col4[i];
    float4 v = adj_vals4[i];
    int p;
    p = atomicAdd(&cursor[r.x], 1); sc[row_start[r.x] + p] = make_int2(c.x, __float_as_int(v.x));
    p = atomicAdd(&cursor[r.y], 1); sc[row_start[r.y] + p] = make_int2(c.y, __float_as_int(v.y));
    p = atomicAdd(&cursor[r.z], 1); sc[row_start[r.z] + p] = make_int2(c.z, __float_as_int(v.z));
    p = atomicAdd(&cursor[r.w], 1); sc[row_start[r.w] + p] = make_int2(c.w, __float_as_int(v.w));
}

// ---------------- aggregation: wave-per-edge-subset, 16B/lane gathers ----------------
__global__ __launch_bounds__(256) void agg_ln_v2(
    const int* __restrict__ row_start, const int2* __restrict__ sc,
    const unsigned short* __restrict__ support,
    const float* __restrict__ bias, const float* __restrict__ gamma,
    const float* __restrict__ beta, float* __restrict__ out)
{
    const int n = blockIdx.x;
    const int t = threadIdx.x;
    const int w = t >> 6;            // wave 0..3
    const int l = t & 63;            // lane: owns dims [8l, 8l+8)
    const int s = row_start[n];
    const int e = row_start[n + 1];

    const unsigned short* supp_l = support + l * 8;

    float acc[8] = {};
    int i = s + w;
    for (; i + 4 < e; i += 8) {
        int2 p0 = sc[i];
        int2 p1 = sc[i + 4];
        u32x4 u0 = *(const u32x4*)(supp_l + p0.x * EMBED);
        u32x4 u1 = *(const u32x4*)(supp_l + p1.x * EMBED);
        float v0 = __int_as_float(p0.y);
        float v1 = __int_as_float(p1.y);
#pragma unroll
        for (int j = 0; j < 4; ++j) {
            unsigned int a = u0[j];
            acc[2 * j]     = fmaf(v0, __uint_as_float(a << 16), acc[2 * j]);
            acc[2 * j + 1] = fmaf(v0, __uint_as_float(a & 0xffff0000u), acc[2 * j + 1]);
        }
#pragma unroll
        for (int j = 0; j < 4; ++j) {
            unsigned int a = u1[j];
            acc[2 * j]     = fmaf(v1, __uint_as_float(a << 16), acc[2 * j]);
            acc[2 * j + 1] = fmaf(v1, __uint_as_float(a & 0xffff0000u), acc[2 * j + 1]);
        }
    }
    if (i < e) {
        int2 p0 = sc[i];
        u32x4 u0 = *(const u32x4*)(supp_l + p0.x * EMBED);
        float v0 = __int_as_float(p0.y);
#pragma unroll
        for (int j = 0; j < 4; ++j) {
            unsigned int a = u0[j];
            acc[2 * j]     = fmaf(v0, __uint_as_float(a << 16), acc[2 * j]);
            acc[2 * j + 1] = fmaf(v0, __uint_as_float(a & 0xffff0000u), acc[2 * j + 1]);
        }
    }

    __shared__ float part[4][EMBED];
    *(f32x4*)&part[w][l * 8]     = *(f32x4*)&acc[0];
    *(f32x4*)&part[w][l * 8 + 4] = *(f32x4*)&acc[4];
    __syncthreads();

    const int d = t * 2;
    float x0 = part[0][d] + part[1][d] + part[2][d] + part[3][d] + bias[d];
    float x1 = part[0][d + 1] + part[1][d + 1] + part[2][d + 1] + part[3][d + 1] + bias[d + 1];

    float s1 = x0 + x1;
    float s2 = x0 * x0 + x1 * x1;
#pragma unroll
    for (int off = 32; off > 0; off >>= 1) {
        s1 += __shfl_down(s1, off, 64);
        s2 += __shfl_down(s2, off, 64);
    }
    __shared__ float ws1[4], ws2[4];
    const int wid = t >> 6, lane = t & 63;
    if (lane == 0) { ws1[wid] = s1; ws2[wid] = s2; }
    __syncthreads();
    if (t == 0) {
        ws1[0] = ws1[0] + ws1[1] + ws1[2] + ws1[3];
        ws2[0] = ws2[0] + ws2[1] + ws2[2] + ws2[3];
    }
    __syncthreads();
    const float mean = ws1[0] * (1.f / 512.f);
    const float var  = ws2[0] * (1.f / 512.f) - mean * mean;
    const float rstd = rsqrtf(var + LN_EPS);

    float2 o;
    o.x = (x0 - mean) * rstd * gamma[d] + beta[d];
    o.y = (x1 - mean) * rstd * gamma[d + 1] + beta[d + 1];
    *(float2*)&out[(long)n * EMBED + d] = o;
}

// ---------------- launch ----------------
extern "C" void kernel_launch(void* const* d_in, const int* in_sizes, int n_in,
                              void* d_out, int out_size, void* d_ws, size_t ws_size,
                              hipStream_t stream)
{
    const int*   user_ids = (const int*)  d_in[0];
    const int*   adj_row  = (const int*)  d_in[1];
    const int*   adj_col  = (const int*)  d_in[2];
    const float* adj_vals = (const float*)d_in[3];
    const float* emb      = (const float*)d_in[4];
    const float* W        = (const float*)d_in[5];
    const float* bias     = (const float*)d_in[6];
    const float* gamma    = (const float*)d_in[7];
    const float* beta     = (const float*)d_in[8];
    float* out = (float*)d_out;

    char* ws = (char*)d_ws;
    size_t off = 0;
    unsigned short* support = (unsigned short*)(ws + off); off += (size_t)N_NODES * EMBED * 2; // 32 MB
    unsigned short* Wt      = (unsigned short*)(ws + off); off += (size_t)EMBED * EMBED * 2;   // 512 KB
    int2*  sc        = (int2*) (ws + off); off += (size_t)NNZ_TOT * 8;                         // 8 MB
    int*   row_start = (int*)  (ws + off); off += (size_t)(N_NODES + 4) * 4;
    int*   counts    = (int*)  (ws + off); off += (size_t)N_NODES * 4;
    int*   cursor    = (int*)  (ws + off); off += (size_t)N_NODES * 4;   // contiguous with counts
    (void)off; (void)ws_size; (void)in_sizes; (void)n_in; (void)out_size;

    zero_ints<<<(2 * N_NODES + 255) / 256, 256, 0, stream>>>(counts, 2 * N_NODES);

    wt_kernel<<<dim3(16, 16), 256, 0, stream>>>(W, Wt);

    gemm_mfma<<<dim3(EMBED / 128, N_NODES / 128), 256, 0, stream>>>(user_ids, emb, Wt, support);

    hist_kernel<<<NNZ_TOT / 4 / 256, 256, 0, stream>>>((const int4*)adj_row, counts);
    scan_kernel<<<1, 1024, 0, stream>>>(counts, row_start);
    scatter_kernel<<<NNZ_TOT / 4 / 256, 256, 0, stream>>>((const int4*)adj_row, (const int4*)adj_col,
                                                          (const float4*)adj_vals,
                                                          row_start, cursor, sc);

    agg_ln_v2<<<N_NODES, 256, 0, stream>>>(row_start, sc, support,
                                           bias, gamma, beta, out);
}